// Round 8
// baseline (514.398 us; speedup 1.0000x reference)
//
#include <hip/hip_runtime.h>
#include <math.h>

#define NN 50000
#define EE 800000
#define ETOT (EE + NN)
#define NGR 64
#define DD 128
#define NCL 10

typedef __attribute__((ext_vector_type(16))) float float16_t;
typedef __attribute__((ext_vector_type(8)))  __bf16 bf16x8;

// ---------------- device helpers ----------------
__device__ __forceinline__ float siluf(float x){ return x / (1.f + __expf(-x)); }

__device__ __forceinline__ unsigned f2bf(float f){
  union { float f; unsigned u; } v; v.f = f;
  unsigned r = v.u + 0x7fffu + ((v.u >> 16) & 1u);
  return (r >> 16) & 0xffffu;
}

// 8 KAN features of scalar x: [silu(x), B0..B6] (float version for readout)
__device__ __forceinline__ void kan_feats(float x, float* f8){
  f8[0] = siluf(x);
  float u = 2.f*x + 5.f;
  int cell = -1;
  float n0=0.f,n1=0.f,n2=0.f,n3=0.f;
  if (u >= 0.f && u < 10.f){
    cell = (int)u;
    float t = u - (float)cell;
    float t2 = t*t, t3 = t2*t;
    float omt = 1.f - t;
    const float s6 = 1.f/6.f;
    n0 = t3*s6;
    n1 = s6*(1.f + 3.f*t + 3.f*t2 - 3.f*t3);
    n2 = s6*(4.f - 6.f*t2 + 3.f*t3);
    n3 = omt*omt*omt*s6;
  }
#pragma unroll
  for (int j=0;j<7;++j){
    int k = cell - j;
    float v = (k==0)?n0:((k==1)?n1:((k==2)?n2:((k==3)?n3:0.f)));
    f8[1+j] = v;
  }
}

// Packed bf16 A-fragment of scalar x: us[0..7] = [silu, B0..B6] via 64-bit shift.
__device__ __forceinline__ int4 kan_feats_pack(float x){
  unsigned sbf = f2bf(siluf(x));
  float u = 2.f*x + 5.f;
  bool valid = (u >= 0.f) && (u < 10.f);
  float uc = valid ? u : 0.f;
  int cell = (int)uc;
  float t = uc - (float)cell;
  float t2 = t*t, t3 = t2*t, omt = 1.f - t;
  const float s6 = 1.f/6.f;
  float n0 = t3*s6;
  float n1 = s6*(1.f + 3.f*t + 3.f*t2 - 3.f*t3);
  float n2 = s6*(4.f - 6.f*t2 + 3.f*t3);
  float n3 = omt*omt*omt*s6;
  unsigned p0=f2bf(n0), p1=f2bf(n1), p2=f2bf(n2), p3=f2bf(n3);
  unsigned long long P = ((unsigned long long)(p1 | (p0<<16)) << 32)
                       |  (unsigned long long)(p3 | (p2<<16));
  int sh = cell*16 - 48;
  unsigned long long shl    = P << (sh & 63);
  unsigned long long shrhi  = P >> ((64 - sh) & 63);
  unsigned long long shllo2 = P << ((sh - 64) & 63);
  unsigned long long shrlo  = P >> ((-sh) & 63);
  unsigned long long F0, F1;
  if (sh < 0)       { F0 = shrlo; F1 = 0ull; }
  else if (sh < 64) { F0 = shl;   F1 = (sh==0)? 0ull : shrhi; }
  else              { F0 = 0ull;  F1 = shllo2; }
  if (!valid){ F0 = 0ull; F1 = 0ull; }
  unsigned w0 = ((unsigned)(F0 & 0xffffull) << 16) | sbf;
  unsigned w1 = (unsigned)((F0 >> 16) & 0xffffffffull);
  unsigned w2 = (unsigned)((F0 >> 48) & 0xffffull) | (((unsigned)(F1 & 0xffffull)) << 16);
  unsigned w3 = (unsigned)((F1 >> 16) & 0xffffffffull);
  return make_int4((int)w0,(int)w1,(int)w2,(int)w3);
}

// ---------------- CSR build (dst-indexed) ----------------
__global__ void hist_kernel(const int* __restrict__ ei, int* __restrict__ deg){
  int e = blockIdx.x*256 + threadIdx.x;
  if (e >= ETOT) return;
  int dst = (e < EE) ? ei[EE + e] : (e - EE);
  atomicAdd(&deg[dst], 1);
}

__global__ void scan1_kernel(const int* __restrict__ deg, int* __restrict__ offs, int* __restrict__ part){
  __shared__ int sh[256];
  int tid = threadIdx.x;
  int i = blockIdx.x*256 + tid;
  int v = (i < NN) ? deg[i] : 0;
  sh[tid] = v; __syncthreads();
  for (int o=1;o<256;o<<=1){
    int t2 = (tid >= o) ? sh[tid - o] : 0;
    __syncthreads();
    sh[tid] += t2;
    __syncthreads();
  }
  int incl = sh[tid];
  if (i < NN) offs[i] = incl - v;
  if (tid == 255) part[blockIdx.x] = incl;
}

__global__ void scan2_kernel(int* __restrict__ part, int nb){
  __shared__ int sh[256];
  int tid = threadIdx.x;
  int v = (tid < nb) ? part[tid] : 0;
  sh[tid] = v; __syncthreads();
  for (int o=1;o<256;o<<=1){
    int t2 = (tid >= o) ? sh[tid - o] : 0;
    __syncthreads();
    sh[tid] += t2;
    __syncthreads();
  }
  if (tid < nb) part[tid] = sh[tid] - v;
}

__global__ void scan3_kernel(int* __restrict__ offs, const int* __restrict__ part, int* __restrict__ cursor){
  int i = blockIdx.x*256 + threadIdx.x;
  if (i >= NN) return;
  int o = offs[i] + part[blockIdx.x];
  offs[i] = o;
  cursor[i] = o;
}

// Fill v3: XCD-partitioned dst ownership. Group g = blockIdx&7 (one XCD under the
// round-robin heuristic); its 32 blocks collectively scan ALL edges, committing
// only dst in [g*6250,(g+1)*6250). Each csr window (425 KB) is then written by a
// single XCD's L2 -> 64B lines accumulate all 16 entries before writeback.
// Reads are 8x-replicated (54 MB) but L3-served. Correctness never depends on
// the block->XCD mapping.
__global__ __launch_bounds__(256) void fill_kernel(const int* __restrict__ ei,
                                                   int* __restrict__ cursor,
                                                   int* __restrict__ csr){
  const int g  = blockIdx.x & 7;
  const int q  = blockIdx.x >> 3;          // 0..31
  const int lo = g*6250, hi = lo + 6250;
  const int chunk = (ETOT + 31) >> 5;      // 26563
  int e0 = q*chunk;
  int e1 = e0 + chunk; if (e1 > ETOT) e1 = ETOT;
  for (int e = e0 + threadIdx.x; e < e1; e += 256){
    int src, dst;
    if (e < EE){ src = ei[e]; dst = ei[EE + e]; } else { src = e - EE; dst = src; }
    if (dst >= lo && dst < hi){
      int pos = atomicAdd(&cursor[dst], 1);
      csr[pos] = src;
    }
  }
}

// ---------------- fold weights into bf16, MFMA-fragment order ----------------
__global__ void build_wfrag(const float* __restrict__ bw, const float* __restrict__ sw,
                            const float* __restrict__ sc, unsigned short* __restrict__ wfrag){
  int idx = blockIdx.x*256 + threadIdx.x;
  if (idx >= 3*128*1024) return;
  int k = idx & 1023;
  int o = (idx >> 10) & 127;
  int l = idx >> 17;
  int i = k >> 3, f = k & 7;
  int oi = (l*DD + o)*DD + i;
  float w = (f == 0) ? bw[oi] : sw[oi*7 + (f-1)] * sc[oi];
  int s = k >> 6;
  int sl = (k >> 4) & 3, half = (k >> 3) & 1, j = k & 7;
  int ntile = o >> 5, n = o & 31;
  int dst = l*131072 + s*8192 + (((ntile*4 + sl)*64) + half*32 + n)*8 + j;
  wfrag[dst] = (unsigned short)f2bf(w);
}

// ---------------- fused KAN feats + GEMM + pack + attention logits ----------------
__global__ __launch_bounds__(256) void kan_gemm(const float* __restrict__ xin,
                                                const unsigned short* __restrict__ wfrag,
                                                const float* __restrict__ attS,
                                                const float* __restrict__ attD,
                                                unsigned int* __restrict__ hpack,
                                                float* __restrict__ asrc,
                                                float* __restrict__ adst, int layer)
{
  __shared__ __align__(16) float xs[64*132];
  __shared__ __align__(16) unsigned short Afrag[2][4096];
  const int t    = threadIdx.x;
  const int lane = t & 63;
  const int w    = t >> 6;
  const int half = lane >> 5;
  const int mn   = lane & 31;
  const int row0 = blockIdx.x * 64;
  const int r_my = t & 63;
  const int il0  = t >> 6;
  const unsigned short* wl = wfrag + layer*131072;

#pragma unroll
  for (int q=0;q<8;++q){
    int p = q*256 + t;
    int r = p >> 5, c4 = p & 31;
    int grow = row0 + r;
    float4 v = make_float4(0.f,0.f,0.f,0.f);
    if (grow < NN) v = *(const float4*)(xin + (size_t)grow*DD + c4*4);
    *(float4*)(&xs[r*132 + c4*4]) = v;
  }
  __syncthreads();

  float16_t acc[2];
#pragma unroll
  for (int i=0;i<16;++i){ acc[0][i]=0.f; acc[1][i]=0.f; }

  int4 Bc[4], Bn[4];
#pragma unroll
  for (int sl=0;sl<4;++sl)
    Bc[sl] = *(const int4*)(wl + ((w*4+sl)*64 + lane)*8);

  const int foa = (((r_my>>5)*8 + il0)*32 + (r_my&31))*8;
  const int fob = (((r_my>>5)*8 + il0+4)*32 + (r_my&31))*8;
  {
    int4 Pa = kan_feats_pack(xs[r_my*132 + il0]);
    int4 Pb = kan_feats_pack(xs[r_my*132 + il0 + 4]);
    *(int4*)(&Afrag[0][foa]) = Pa;
    *(int4*)(&Afrag[0][fob]) = Pb;
  }
  __syncthreads();

  for (int s=0; s<16; ++s){
    if (s < 15){
      const unsigned short* wsrc = wl + (s+1)*8192;
#pragma unroll
      for (int sl=0;sl<4;++sl)
        Bn[sl] = *(const int4*)(wsrc + ((w*4+sl)*64 + lane)*8);
      int4 Pa = kan_feats_pack(xs[r_my*132 + (s+1)*8 + il0]);
      int4 Pb = kan_feats_pack(xs[r_my*132 + (s+1)*8 + il0 + 4]);
      *(int4*)(&Afrag[(s+1)&1][foa]) = Pa;
      *(int4*)(&Afrag[(s+1)&1][fob]) = Pb;
    }
    const unsigned short* A = Afrag[s&1];
#pragma unroll
    for (int sl=0; sl<4; ++sl){
      int4 a0i = *(const int4*)(A + (((0*8 + sl*2 + half)*32) + mn)*8);
      int4 a1i = *(const int4*)(A + (((1*8 + sl*2 + half)*32) + mn)*8);
      bf16x8 b = __builtin_bit_cast(bf16x8, Bc[sl]);
      acc[0] = __builtin_amdgcn_mfma_f32_32x32x16_bf16(__builtin_bit_cast(bf16x8, a0i), b, acc[0], 0, 0, 0);
      acc[1] = __builtin_amdgcn_mfma_f32_32x32x16_bf16(__builtin_bit_cast(bf16x8, a1i), b, acc[1], 0, 0, 0);
    }
#pragma unroll
    for (int sl=0;sl<4;++sl) Bc[sl] = Bn[sl];
    __syncthreads();
  }

  unsigned short* hs = (unsigned short*)xs;
#pragma unroll
  for (int mt=0; mt<2; ++mt){
#pragma unroll
    for (int reg=0; reg<16; ++reg){
      int row = mt*32 + (reg&3) + 8*(reg>>2) + 4*half;
      int col = w*32 + mn;
      hs[row*136 + col] = (unsigned short)f2bf(acc[mt][reg]);
    }
  }
  __syncthreads();
#pragma unroll
  for (int q=0;q<4;++q){
    int p = q*256 + t;
    int row = p >> 4, u4 = p & 15;
    uint4 v = *(const uint4*)((const unsigned int*)(hs + row*136) + u4*4);
    int grow = row0 + row;
    if (grow < NN) *(uint4*)(hpack + (size_t)grow*64 + u4*4) = v;
  }
  {
    int r = t >> 2, h = t & 3;
    const unsigned* hrow = (const unsigned*)(hs + r*136) + h*16;
    const float* ws = attS + (layer*4 + h)*32;
    const float* wd = attD + (layer*4 + h)*32;
    float ss = 0.f, sd = 0.f;
#pragma unroll
    for (int j=0;j<16;++j){
      unsigned u = hrow[j];
      float flo = __uint_as_float(u << 16);
      float fhi = __uint_as_float(u & 0xffff0000u);
      ss += flo*ws[2*j] + fhi*ws[2*j+1];
      sd += flo*wd[2*j] + fhi*wd[2*j+1];
    }
    int grow = row0 + r;
    if (grow < NN){ asrc[grow*4 + h] = ss; adst[grow*4 + h] = sd; }
  }
}

// ---------------- GAT aggregation v3: register-resident edges, batched gathers ----------------
__global__ __launch_bounds__(256) void attn_kernel(
    const unsigned int* __restrict__ hpack, const float* __restrict__ asrc, const float* __restrict__ adst,
    const int* __restrict__ offs, const int* __restrict__ deg, const int* __restrict__ csr,
    const float* __restrict__ bias, float* __restrict__ hout, int layer)
{
  const int wave = threadIdx.x >> 6;
  const int lane = threadIdx.x & 63;
  const int n = blockIdx.x*4 + wave;
  if (n >= NN) return;
  const int st = offs[n];
  const int d  = deg[n];
  const int eL = lane >> 2, h = lane & 3;
  const float adh = adst[n*4 + h];

  int   srcv[4];
  float ev[4];
  float mL = -3.4e38f;
#pragma unroll
  for (int c=0;c<4;++c){
    srcv[c] = 0; ev[c] = -3.4e38f;
    int e = c*16 + eL;
    if (e < d){
      int s2 = csr[st + e];
      srcv[c] = s2;
      float e0 = asrc[s2*4 + h] + adh;
      ev[c] = (e0 > 0.f) ? e0 : 0.2f*e0;
      mL = fmaxf(mL, ev[c]);
    }
  }
  for (int c=64; c<d; c+=16){
    int e = c + eL;
    if (e < d){
      int s2 = csr[st + e];
      float e0 = asrc[s2*4 + h] + adh;
      float evv = (e0 > 0.f) ? e0 : 0.2f*e0;
      mL = fmaxf(mL, evv);
    }
  }
#pragma unroll
  for (int o=4;o<64;o<<=1) mL = fmaxf(mL, __shfl_xor(mL, o));

  float av4[4];
  float sL = 0.f;
#pragma unroll
  for (int c=0;c<4;++c){ av4[c] = __expf(ev[c] - mL); sL += av4[c]; }
  for (int c=64; c<d; c+=16){
    int e = c + eL;
    if (e < d){
      int s2 = csr[st + e];
      float e0 = asrc[s2*4 + h] + adh;
      float evv = (e0 > 0.f) ? e0 : 0.2f*e0;
      sL += __expf(evv - mL);
    }
  }
#pragma unroll
  for (int o=4;o<64;o<<=1) sL += __shfl_xor(sL, o);
  const float inv = 1.f/(sL + 1e-16f);

  const int hq = lane >> 4;
  float accL = 0.f, accH = 0.f;
#pragma unroll
  for (int c=0;c<4;++c){
    if (c*16 < d){
      float ac = av4[c] * inv;
      int lim = d - c*16; if (lim > 16) lim = 16;
      unsigned uv[16]; float aj[16];
#pragma unroll
      for (int j=0;j<16;++j){
        int sj = __shfl(srcv[c], j*4);
        aj[j]  = __shfl(ac,      j*4 + hq);
        if (j < lim) uv[j] = hpack[(size_t)sj*64 + lane];
        else         uv[j] = 0u;
      }
#pragma unroll
      for (int j=0;j<16;++j){
        accL = fmaf(aj[j], __uint_as_float(uv[j] << 16),         accL);
        accH = fmaf(aj[j], __uint_as_float(uv[j] & 0xffff0000u), accH);
      }
    }
  }
  for (int c=64; c<d; c+=16){
    int e = c + eL;
    int s2 = 0; float al = 0.f;
    if (e < d){
      s2 = csr[st + e];
      float e0 = asrc[s2*4 + h] + adh;
      float evv = (e0 > 0.f) ? e0 : 0.2f*e0;
      al = __expf(evv - mL) * inv;
    }
    int lim = d - c; if (lim > 16) lim = 16;
    for (int j=0;j<lim;++j){
      int sj = __shfl(s2, j*4);
      float aH = __shfl(al, j*4 + hq);
      unsigned u = hpack[(size_t)sj*64 + lane];
      accL = fmaf(aH, __uint_as_float(u << 16),         accL);
      accH = fmaf(aH, __uint_as_float(u & 0xffff0000u), accH);
    }
  }
  float2 bv = *(const float2*)(bias + layer*DD + 2*lane);
  float o0 = siluf(accL + bv.x);
  float o1 = siluf(accH + bv.y);
  *(float2*)(hout + (size_t)n*DD + 2*lane) = make_float2(o0, o1);
}

// ---------------- global_add_pool (batch is sorted) ----------------
__global__ __launch_bounds__(128) void pool_kernel(const float* __restrict__ h,
    const int* __restrict__ batch, float* __restrict__ pooled)
{
  int c = threadIdx.x;
  int n0 = blockIdx.x*128;
  float sum = 0.f; int cur = -1;
  for (int r=0;r<128;++r){
    int n = n0 + r;
    if (n >= NN) break;
    int g = batch[n];
    if (g != cur){
      if (cur >= 0) atomicAdd(&pooled[cur*DD + c], sum);
      cur = g; sum = 0.f;
    }
    sum += h[n*DD + c];
  }
  if (cur >= 0) atomicAdd(&pooled[cur*DD + c], sum);
}

// ---------------- KAN readout + log_softmax (1 block per graph) ----------------
__global__ __launch_bounds__(64) void readout_kernel(const float* __restrict__ pooled,
    const float* __restrict__ bw, const float* __restrict__ sw, const float* __restrict__ sc,
    float* __restrict__ out)
{
  int g = blockIdx.x, lane = threadIdx.x;
  float xa = pooled[g*DD + lane];
  float xb = pooled[g*DD + lane + 64];
  float fa[8], fb[8];
  kan_feats(xa, fa);
  kan_feats(xb, fb);
  float logits[NCL];
#pragma unroll
  for (int c=0;c<NCL;++c){
    int ia = c*DD + lane, ib = ia + 64;
    float sca = sc[ia], scb = sc[ib];
    float p = fa[0]*bw[ia] + fb[0]*bw[ib];
#pragma unroll
    for (int f=1;f<8;++f)
      p += fa[f]*sw[ia*7 + f-1]*sca + fb[f]*sw[ib*7 + f-1]*scb;
#pragma unroll
    for (int o=1;o<64;o<<=1) p += __shfl_xor(p, o);
    logits[c] = p;
  }
  float mx = logits[0];
#pragma unroll
  for (int c=1;c<NCL;++c) mx = fmaxf(mx, logits[c]);
  float lse = 0.f;
#pragma unroll
  for (int c=0;c<NCL;++c) lse += __expf(logits[c]-mx);
  lse = mx + logf(lse);
  if (lane < NCL){
    float v = 0.f;
#pragma unroll
    for (int c=0;c<NCL;++c) if (lane == c) v = logits[c] - lse;
    out[g*NCL + lane] = v;
  }
}

// ---------------- host ----------------
extern "C" void kernel_launch(void* const* d_in, const int* in_sizes, int n_in,
                              void* d_out, int out_size, void* d_ws, size_t ws_size,
                              hipStream_t stream)
{
  const float* x        = (const float*)d_in[0];
  const int*   ei       = (const int*)  d_in[1];
  const int*   batch    = (const int*)  d_in[2];
  const float* base_w   = (const float*)d_in[3];
  const float* spline_w = (const float*)d_in[4];
  const float* scaler   = (const float*)d_in[5];
  const float* att_src  = (const float*)d_in[6];
  const float* att_dst  = (const float*)d_in[7];
  const float* bias     = (const float*)d_in[8];
  const float* ro_bw    = (const float*)d_in[9];
  const float* ro_sw    = (const float*)d_in[10];
  const float* ro_sc    = (const float*)d_in[11];
  float* out = (float*)d_out;

  char* p = (char*)d_ws;
  auto alloc = [&](size_t bytes)->char* {
    char* r = p;
    p += (bytes + 255) & ~(size_t)255;
    return r;
  };
  unsigned int* hpack = (unsigned int*)alloc((size_t)50048*64*4);
  float* hbuf   = (float*)alloc((size_t)NN*DD*4);
  unsigned short* wfrag = (unsigned short*)alloc((size_t)3*131072*2);
  float* asrc   = (float*)alloc((size_t)NN*4*4);
  float* adst   = (float*)alloc((size_t)NN*4*4);
  float* pooled = (float*)alloc((size_t)NGR*DD*4);
  int*   deg    = (int*)alloc((size_t)NN*4);
  int*   offs   = (int*)alloc((size_t)NN*4);
  int*   cursor = (int*)alloc((size_t)NN*4);
  int*   csr    = (int*)alloc((size_t)ETOT*4);
  int*   part   = (int*)alloc((size_t)256*4);

  const int nbs = (NN + 255)/256;
  hipMemsetAsync(deg, 0, (size_t)NN*sizeof(int), stream);
  hist_kernel <<<(ETOT+255)/256, 256, 0, stream>>>(ei, deg);
  scan1_kernel<<<nbs, 256, 0, stream>>>(deg, offs, part);
  scan2_kernel<<<1,   256, 0, stream>>>(part, nbs);
  scan3_kernel<<<nbs, 256, 0, stream>>>(offs, part, cursor);
  fill_kernel <<<256, 256, 0, stream>>>(ei, cursor, csr);
  build_wfrag <<<(3*128*1024)/256, 256, 0, stream>>>(base_w, spline_w, scaler, wfrag);

  const float* cur = x;
  for (int l=0; l<3; ++l){
    kan_gemm   <<<(NN+63)/64, 256, 0, stream>>>(cur, wfrag, att_src, att_dst,
                                                hpack, asrc, adst, l);
    attn_kernel<<<(NN+3)/4,   256, 0, stream>>>(hpack, asrc, adst, offs, deg, csr,
                                                bias, hbuf, l);
    cur = hbuf;
  }
  hipMemsetAsync(pooled, 0, (size_t)NGR*DD*sizeof(float), stream);
  pool_kernel   <<<(NN+127)/128, 128, 0, stream>>>(hbuf, batch, pooled);
  readout_kernel<<<NGR, 64, 0, stream>>>(pooled, ro_bw, ro_sw, ro_sc, out);
}

// Round 9
// 459.655 us; speedup vs baseline: 1.1191x; 1.1191x over previous
//
#include <hip/hip_runtime.h>
#include <math.h>

#define NN 50000
#define EE 800000
#define ETOT (EE + NN)
#define NGR 64
#define DD 128
#define NCL 10

#define NBUK 128
#define BNODES 391            // 128*391 = 50048 >= NN
#define P1CH 3321             // ceil(ETOT/256)
#define P2CAP 8704            // LDS entry cap per bucket (mean ~6650)

typedef __attribute__((ext_vector_type(16))) float float16_t;
typedef __attribute__((ext_vector_type(8)))  __bf16 bf16x8;

// ---------------- device helpers ----------------
__device__ __forceinline__ float siluf(float x){ return x / (1.f + __expf(-x)); }

__device__ __forceinline__ unsigned f2bf(float f){
  union { float f; unsigned u; } v; v.f = f;
  unsigned r = v.u + 0x7fffu + ((v.u >> 16) & 1u);
  return (r >> 16) & 0xffffu;
}

// 8 KAN features of scalar x: [silu(x), B0..B6] (float version for readout)
__device__ __forceinline__ void kan_feats(float x, float* f8){
  f8[0] = siluf(x);
  float u = 2.f*x + 5.f;
  int cell = -1;
  float n0=0.f,n1=0.f,n2=0.f,n3=0.f;
  if (u >= 0.f && u < 10.f){
    cell = (int)u;
    float t = u - (float)cell;
    float t2 = t*t, t3 = t2*t;
    float omt = 1.f - t;
    const float s6 = 1.f/6.f;
    n0 = t3*s6;
    n1 = s6*(1.f + 3.f*t + 3.f*t2 - 3.f*t3);
    n2 = s6*(4.f - 6.f*t2 + 3.f*t3);
    n3 = omt*omt*omt*s6;
  }
#pragma unroll
  for (int j=0;j<7;++j){
    int k = cell - j;
    float v = (k==0)?n0:((k==1)?n1:((k==2)?n2:((k==3)?n3:0.f)));
    f8[1+j] = v;
  }
}

// Packed bf16 A-fragment of scalar x: us[0..7] = [silu, B0..B6] via 64-bit shift.
__device__ __forceinline__ int4 kan_feats_pack(float x){
  unsigned sbf = f2bf(siluf(x));
  float u = 2.f*x + 5.f;
  bool valid = (u >= 0.f) && (u < 10.f);
  float uc = valid ? u : 0.f;
  int cell = (int)uc;
  float t = uc - (float)cell;
  float t2 = t*t, t3 = t2*t, omt = 1.f - t;
  const float s6 = 1.f/6.f;
  float n0 = t3*s6;
  float n1 = s6*(1.f + 3.f*t + 3.f*t2 - 3.f*t3);
  float n2 = s6*(4.f - 6.f*t2 + 3.f*t3);
  float n3 = omt*omt*omt*s6;
  unsigned p0=f2bf(n0), p1=f2bf(n1), p2=f2bf(n2), p3=f2bf(n3);
  unsigned long long P = ((unsigned long long)(p1 | (p0<<16)) << 32)
                       |  (unsigned long long)(p3 | (p2<<16));
  int sh = cell*16 - 48;
  unsigned long long shl    = P << (sh & 63);
  unsigned long long shrhi  = P >> ((64 - sh) & 63);
  unsigned long long shllo2 = P << ((sh - 64) & 63);
  unsigned long long shrlo  = P >> ((-sh) & 63);
  unsigned long long F0, F1;
  if (sh < 0)       { F0 = shrlo; F1 = 0ull; }
  else if (sh < 64) { F0 = shl;   F1 = (sh==0)? 0ull : shrhi; }
  else              { F0 = 0ull;  F1 = shllo2; }
  if (!valid){ F0 = 0ull; F1 = 0ull; }
  unsigned w0 = ((unsigned)(F0 & 0xffffull) << 16) | sbf;
  unsigned w1 = (unsigned)((F0 >> 16) & 0xffffffffull);
  unsigned w2 = (unsigned)((F0 >> 48) & 0xffffull) | (((unsigned)(F1 & 0xffffull)) << 16);
  unsigned w3 = (unsigned)((F1 >> 16) & 0xffffffffull);
  return make_int4((int)w0,(int)w1,(int)w2,(int)w3);
}

// ---------------- CSR build (dst-indexed) ----------------
__global__ void hist_kernel(const int* __restrict__ ei, int* __restrict__ deg){
  int e = blockIdx.x*256 + threadIdx.x;
  if (e >= ETOT) return;
  int dst = (e < EE) ? ei[EE + e] : (e - EE);
  atomicAdd(&deg[dst], 1);
}

__global__ void scan1_kernel(const int* __restrict__ deg, int* __restrict__ offs, int* __restrict__ part){
  __shared__ int sh[256];
  int tid = threadIdx.x;
  int i = blockIdx.x*256 + tid;
  int v = (i < NN) ? deg[i] : 0;
  sh[tid] = v; __syncthreads();
  for (int o=1;o<256;o<<=1){
    int t2 = (tid >= o) ? sh[tid - o] : 0;
    __syncthreads();
    sh[tid] += t2;
    __syncthreads();
  }
  int incl = sh[tid];
  if (i < NN) offs[i] = incl - v;
  if (tid == 255) part[blockIdx.x] = incl;
}

__global__ void scan2_kernel(int* __restrict__ part, int nb){
  __shared__ int sh[256];
  int tid = threadIdx.x;
  int v = (tid < nb) ? part[tid] : 0;
  sh[tid] = v; __syncthreads();
  for (int o=1;o<256;o<<=1){
    int t2 = (tid >= o) ? sh[tid - o] : 0;
    __syncthreads();
    sh[tid] += t2;
    __syncthreads();
  }
  if (tid < nb) part[tid] = sh[tid] - v;
}

__global__ void scan3_kernel(int* __restrict__ offs, const int* __restrict__ part, int* __restrict__ cursor){
  int i = blockIdx.x*256 + threadIdx.x;
  if (i >= NN) return;
  int o = offs[i] + part[blockIdx.x];
  offs[i] = o;
  cursor[i] = o;
}

__global__ void binit_kernel(const int* __restrict__ offs, int* __restrict__ bcur){
  int b = threadIdx.x;
  if (b < NBUK) bcur[b] = offs[b*BNODES];
}

// CSR pass 1 (multisplit): each block owns a contiguous edge slice; LDS-sorts it
// by dst-bucket (128 buckets of 391 nodes) and flushes bucket-contiguous runs to
// tmp, reserving space with ONE global atomic per (block,bucket). All global
// writes are coalesced runs -> no cache-line amplification.
// tmp entry: (bucket<<25) | (dstLocal<<16) | src
__global__ __launch_bounds__(256) void binpass_kernel(const int* __restrict__ ei,
                                                      int* __restrict__ bcur,
                                                      unsigned* __restrict__ tmp){
  __shared__ int cnt[NBUK], lexcl[NBUK], gbase[NBUK], lcur[NBUK];
  __shared__ int sc[NBUK];
  __shared__ unsigned entries[P1CH + 7];
  const int t = threadIdx.x;
  const int e0 = blockIdx.x * P1CH;
  int e1 = e0 + P1CH; if (e1 > ETOT) e1 = ETOT;
  const int total = e1 - e0;

  if (t < NBUK){ cnt[t] = 0; lcur[t] = 0; }
  __syncthreads();

  unsigned myE[14]; int myB[14]; int myN = 0;
  for (int e = e0 + t; e < e1; e += 256){
    int src, dst;
    if (e < EE){ src = ei[e]; dst = ei[EE + e]; } else { src = e - EE; dst = src; }
    int b = dst / BNODES;
    int dl = dst - b*BNODES;
    myE[myN] = ((unsigned)b << 25) | ((unsigned)dl << 16) | (unsigned)src;
    myB[myN] = b;
    myN++;
    atomicAdd(&cnt[b], 1);
  }
  __syncthreads();

  // exclusive scan of cnt over 128 buckets
  if (t < NBUK) sc[t] = cnt[t];
  __syncthreads();
  for (int o=1;o<NBUK;o<<=1){
    int v = 0;
    if (t < NBUK && t >= o) v = sc[t - o];
    __syncthreads();
    if (t < NBUK) sc[t] += v;
    __syncthreads();
  }
  if (t < NBUK) lexcl[t] = sc[t] - cnt[t];
  __syncthreads();

  // reserve global chunks
  if (t < NBUK && cnt[t] > 0) gbase[t] = atomicAdd(&bcur[t], cnt[t]);
  __syncthreads();

  // place into LDS sorted-by-bucket
  for (int k=0;k<myN;++k){
    int b = myB[k];
    int r = lexcl[b] + atomicAdd(&lcur[b], 1);
    entries[r] = myE[k];
  }
  __syncthreads();

  // flush: consecutive slots -> consecutive tmp positions within a bucket
  for (int s = t; s < total; s += 256){
    unsigned en = entries[s];
    int b = en >> 25;
    int pos = gbase[b] + (s - lexcl[b]);
    tmp[pos] = en;
  }
}

// CSR pass 2: one block per bucket; group the bucket's tmp window by dst in LDS,
// then write the csr window fully coalesced.
__global__ __launch_bounds__(256) void scatter_kernel(const unsigned* __restrict__ tmp,
                                                      const int* __restrict__ offs,
                                                      int* __restrict__ cursor,
                                                      int* __restrict__ csr){
  __shared__ unsigned ebuf[P2CAP];
  __shared__ unsigned sbuf[P2CAP];
  __shared__ int dcnt[BNODES+1], dscan[BNODES+1], dcur[BNODES+1];
  __shared__ int sA[512], sB[512];
  const int t = threadIdx.x;
  const int b = blockIdx.x;
  const int lo = b * BNODES;
  const int start = offs[lo];
  const int end = (b < NBUK-1) ? offs[lo + BNODES] : ETOT;
  const int cnt = end - start;

  if (cnt > P2CAP){
    // fallback (never expected): direct scatter via global cursor
    for (int i = t; i < cnt; i += 256){
      unsigned en = tmp[start + i];
      int node = lo + (int)((en >> 16) & 0x1FF);
      int pos = atomicAdd(&cursor[node], 1);
      csr[pos] = (int)(en & 0xFFFF);
    }
    return;
  }

  for (int i = t; i < cnt; i += 256) ebuf[i] = tmp[start + i];
  for (int i = t; i < BNODES+1; i += 256){ dcnt[i] = 0; dcur[i] = 0; }
  __syncthreads();
  for (int i = t; i < cnt; i += 256){
    int dl = (ebuf[i] >> 16) & 0x1FF;
    atomicAdd(&dcnt[dl], 1);
  }
  __syncthreads();

  // exclusive scan over 392 counters (padded to 512, double-buffered H-S)
  sA[t]       = (t       < BNODES+1) ? dcnt[t]       : 0;
  sA[t + 256] = (t + 256 < BNODES+1) ? dcnt[t + 256] : 0;
  __syncthreads();
  int* sp = sA; int* dp = sB;
  for (int o=1;o<512;o<<=1){
    dp[t]       = sp[t]       + ((t       >= o) ? sp[t - o]       : 0);
    dp[t + 256] = sp[t + 256] + ((t + 256 >= o) ? sp[t + 256 - o] : 0);
    __syncthreads();
    int* tpp = sp; sp = dp; dp = tpp;
  }
  if (t       < BNODES+1) dscan[t]       = sp[t]       - dcnt[t];
  if (t + 256 < BNODES+1) dscan[t + 256] = sp[t + 256] - dcnt[t + 256];
  __syncthreads();

  // LDS scatter by dstLocal
  for (int i = t; i < cnt; i += 256){
    unsigned en = ebuf[i];
    int dl = (en >> 16) & 0x1FF;
    int r = dscan[dl] + atomicAdd(&dcur[dl], 1);
    sbuf[r] = en & 0xFFFFu;
  }
  __syncthreads();
  for (int i = t; i < cnt; i += 256) csr[start + i] = (int)sbuf[i];
}

// ---------------- fold weights into bf16, MFMA-fragment order ----------------
__global__ void build_wfrag(const float* __restrict__ bw, const float* __restrict__ sw,
                            const float* __restrict__ sc, unsigned short* __restrict__ wfrag){
  int idx = blockIdx.x*256 + threadIdx.x;
  if (idx >= 3*128*1024) return;
  int k = idx & 1023;
  int o = (idx >> 10) & 127;
  int l = idx >> 17;
  int i = k >> 3, f = k & 7;
  int oi = (l*DD + o)*DD + i;
  float w = (f == 0) ? bw[oi] : sw[oi*7 + (f-1)] * sc[oi];
  int s = k >> 6;
  int sl = (k >> 4) & 3, half = (k >> 3) & 1, j = k & 7;
  int ntile = o >> 5, n = o & 31;
  int dst = l*131072 + s*8192 + (((ntile*4 + sl)*64) + half*32 + n)*8 + j;
  wfrag[dst] = (unsigned short)f2bf(w);
}

// ---------------- fused KAN feats + GEMM + pack + attention logits ----------------
__global__ __launch_bounds__(256) void kan_gemm(const float* __restrict__ xin,
                                                const unsigned short* __restrict__ wfrag,
                                                const float* __restrict__ attS,
                                                const float* __restrict__ attD,
                                                unsigned int* __restrict__ hpack,
                                                float* __restrict__ asrc,
                                                float* __restrict__ adst, int layer)
{
  __shared__ __align__(16) float xs[64*132];
  __shared__ __align__(16) unsigned short Afrag[2][4096];
  const int t    = threadIdx.x;
  const int lane = t & 63;
  const int w    = t >> 6;
  const int half = lane >> 5;
  const int mn   = lane & 31;
  const int row0 = blockIdx.x * 64;
  const int r_my = t & 63;
  const int il0  = t >> 6;
  const unsigned short* wl = wfrag + layer*131072;

#pragma unroll
  for (int q=0;q<8;++q){
    int p = q*256 + t;
    int r = p >> 5, c4 = p & 31;
    int grow = row0 + r;
    float4 v = make_float4(0.f,0.f,0.f,0.f);
    if (grow < NN) v = *(const float4*)(xin + (size_t)grow*DD + c4*4);
    *(float4*)(&xs[r*132 + c4*4]) = v;
  }
  __syncthreads();

  float16_t acc[2];
#pragma unroll
  for (int i=0;i<16;++i){ acc[0][i]=0.f; acc[1][i]=0.f; }

  int4 Bc[4], Bn[4];
#pragma unroll
  for (int sl=0;sl<4;++sl)
    Bc[sl] = *(const int4*)(wl + ((w*4+sl)*64 + lane)*8);

  const int foa = (((r_my>>5)*8 + il0)*32 + (r_my&31))*8;
  const int fob = (((r_my>>5)*8 + il0+4)*32 + (r_my&31))*8;
  {
    int4 Pa = kan_feats_pack(xs[r_my*132 + il0]);
    int4 Pb = kan_feats_pack(xs[r_my*132 + il0 + 4]);
    *(int4*)(&Afrag[0][foa]) = Pa;
    *(int4*)(&Afrag[0][fob]) = Pb;
  }
  __syncthreads();

  for (int s=0; s<16; ++s){
    if (s < 15){
      const unsigned short* wsrc = wl + (s+1)*8192;
#pragma unroll
      for (int sl=0;sl<4;++sl)
        Bn[sl] = *(const int4*)(wsrc + ((w*4+sl)*64 + lane)*8);
      int4 Pa = kan_feats_pack(xs[r_my*132 + (s+1)*8 + il0]);
      int4 Pb = kan_feats_pack(xs[r_my*132 + (s+1)*8 + il0 + 4]);
      *(int4*)(&Afrag[(s+1)&1][foa]) = Pa;
      *(int4*)(&Afrag[(s+1)&1][fob]) = Pb;
    }
    const unsigned short* A = Afrag[s&1];
#pragma unroll
    for (int sl=0; sl<4; ++sl){
      int4 a0i = *(const int4*)(A + (((0*8 + sl*2 + half)*32) + mn)*8);
      int4 a1i = *(const int4*)(A + (((1*8 + sl*2 + half)*32) + mn)*8);
      bf16x8 b = __builtin_bit_cast(bf16x8, Bc[sl]);
      acc[0] = __builtin_amdgcn_mfma_f32_32x32x16_bf16(__builtin_bit_cast(bf16x8, a0i), b, acc[0], 0, 0, 0);
      acc[1] = __builtin_amdgcn_mfma_f32_32x32x16_bf16(__builtin_bit_cast(bf16x8, a1i), b, acc[1], 0, 0, 0);
    }
#pragma unroll
    for (int sl=0;sl<4;++sl) Bc[sl] = Bn[sl];
    __syncthreads();
  }

  unsigned short* hs = (unsigned short*)xs;
#pragma unroll
  for (int mt=0; mt<2; ++mt){
#pragma unroll
    for (int reg=0; reg<16; ++reg){
      int row = mt*32 + (reg&3) + 8*(reg>>2) + 4*half;
      int col = w*32 + mn;
      hs[row*136 + col] = (unsigned short)f2bf(acc[mt][reg]);
    }
  }
  __syncthreads();
#pragma unroll
  for (int q=0;q<4;++q){
    int p = q*256 + t;
    int row = p >> 4, u4 = p & 15;
    uint4 v = *(const uint4*)((const unsigned int*)(hs + row*136) + u4*4);
    int grow = row0 + row;
    if (grow < NN) *(uint4*)(hpack + (size_t)grow*64 + u4*4) = v;
  }
  {
    int r = t >> 2, h = t & 3;
    const unsigned* hrow = (const unsigned*)(hs + r*136) + h*16;
    const float* ws = attS + (layer*4 + h)*32;
    const float* wd = attD + (layer*4 + h)*32;
    float ss = 0.f, sd = 0.f;
#pragma unroll
    for (int j=0;j<16;++j){
      unsigned u = hrow[j];
      float flo = __uint_as_float(u << 16);
      float fhi = __uint_as_float(u & 0xffff0000u);
      ss += flo*ws[2*j] + fhi*ws[2*j+1];
      sd += flo*wd[2*j] + fhi*wd[2*j+1];
    }
    int grow = row0 + r;
    if (grow < NN){ asrc[grow*4 + h] = ss; adst[grow*4 + h] = sd; }
  }
}

// ---------------- GAT aggregation v3: register-resident edges, batched gathers ----------------
__global__ __launch_bounds__(256) void attn_kernel(
    const unsigned int* __restrict__ hpack, const float* __restrict__ asrc, const float* __restrict__ adst,
    const int* __restrict__ offs, const int* __restrict__ deg, const int* __restrict__ csr,
    const float* __restrict__ bias, float* __restrict__ hout, int layer)
{
  const int wave = threadIdx.x >> 6;
  const int lane = threadIdx.x & 63;
  const int n = blockIdx.x*4 + wave;
  if (n >= NN) return;
  const int st = offs[n];
  const int d  = deg[n];
  const int eL = lane >> 2, h = lane & 3;
  const float adh = adst[n*4 + h];

  int   srcv[4];
  float ev[4];
  float mL = -3.4e38f;
#pragma unroll
  for (int c=0;c<4;++c){
    srcv[c] = 0; ev[c] = -3.4e38f;
    int e = c*16 + eL;
    if (e < d){
      int s2 = csr[st + e];
      srcv[c] = s2;
      float e0 = asrc[s2*4 + h] + adh;
      ev[c] = (e0 > 0.f) ? e0 : 0.2f*e0;
      mL = fmaxf(mL, ev[c]);
    }
  }
  for (int c=64; c<d; c+=16){
    int e = c + eL;
    if (e < d){
      int s2 = csr[st + e];
      float e0 = asrc[s2*4 + h] + adh;
      float evv = (e0 > 0.f) ? e0 : 0.2f*e0;
      mL = fmaxf(mL, evv);
    }
  }
#pragma unroll
  for (int o=4;o<64;o<<=1) mL = fmaxf(mL, __shfl_xor(mL, o));

  float av4[4];
  float sL = 0.f;
#pragma unroll
  for (int c=0;c<4;++c){ av4[c] = __expf(ev[c] - mL); sL += av4[c]; }
  for (int c=64; c<d; c+=16){
    int e = c + eL;
    if (e < d){
      int s2 = csr[st + e];
      float e0 = asrc[s2*4 + h] + adh;
      float evv = (e0 > 0.f) ? e0 : 0.2f*e0;
      sL += __expf(evv - mL);
    }
  }
#pragma unroll
  for (int o=4;o<64;o<<=1) sL += __shfl_xor(sL, o);
  const float inv = 1.f/(sL + 1e-16f);

  const int hq = lane >> 4;
  float accL = 0.f, accH = 0.f;
#pragma unroll
  for (int c=0;c<4;++c){
    if (c*16 < d){
      float ac = av4[c] * inv;
      int lim = d - c*16; if (lim > 16) lim = 16;
      unsigned uv[16]; float aj[16];
#pragma unroll
      for (int j=0;j<16;++j){
        int sj = __shfl(srcv[c], j*4);
        aj[j]  = __shfl(ac,      j*4 + hq);
        if (j < lim) uv[j] = hpack[(size_t)sj*64 + lane];
        else         uv[j] = 0u;
      }
#pragma unroll
      for (int j=0;j<16;++j){
        accL = fmaf(aj[j], __uint_as_float(uv[j] << 16),         accL);
        accH = fmaf(aj[j], __uint_as_float(uv[j] & 0xffff0000u), accH);
      }
    }
  }
  for (int c=64; c<d; c+=16){
    int e = c + eL;
    int s2 = 0; float al = 0.f;
    if (e < d){
      s2 = csr[st + e];
      float e0 = asrc[s2*4 + h] + adh;
      float evv = (e0 > 0.f) ? e0 : 0.2f*e0;
      al = __expf(evv - mL) * inv;
    }
    int lim = d - c; if (lim > 16) lim = 16;
    for (int j=0;j<lim;++j){
      int sj = __shfl(s2, j*4);
      float aH = __shfl(al, j*4 + hq);
      unsigned u = hpack[(size_t)sj*64 + lane];
      accL = fmaf(aH, __uint_as_float(u << 16),         accL);
      accH = fmaf(aH, __uint_as_float(u & 0xffff0000u), accH);
    }
  }
  float2 bv = *(const float2*)(bias + layer*DD + 2*lane);
  float o0 = siluf(accL + bv.x);
  float o1 = siluf(accH + bv.y);
  *(float2*)(hout + (size_t)n*DD + 2*lane) = make_float2(o0, o1);
}

// ---------------- global_add_pool (batch is sorted) ----------------
__global__ __launch_bounds__(128) void pool_kernel(const float* __restrict__ h,
    const int* __restrict__ batch, float* __restrict__ pooled)
{
  int c = threadIdx.x;
  int n0 = blockIdx.x*128;
  float sum = 0.f; int cur = -1;
  for (int r=0;r<128;++r){
    int n = n0 + r;
    if (n >= NN) break;
    int g = batch[n];
    if (g != cur){
      if (cur >= 0) atomicAdd(&pooled[cur*DD + c], sum);
      cur = g; sum = 0.f;
    }
    sum += h[n*DD + c];
  }
  if (cur >= 0) atomicAdd(&pooled[cur*DD + c], sum);
}

// ---------------- KAN readout + log_softmax (1 block per graph) ----------------
__global__ __launch_bounds__(64) void readout_kernel(const float* __restrict__ pooled,
    const float* __restrict__ bw, const float* __restrict__ sw, const float* __restrict__ sc,
    float* __restrict__ out)
{
  int g = blockIdx.x, lane = threadIdx.x;
  float xa = pooled[g*DD + lane];
  float xb = pooled[g*DD + lane + 64];
  float fa[8], fb[8];
  kan_feats(xa, fa);
  kan_feats(xb, fb);
  float logits[NCL];
#pragma unroll
  for (int c=0;c<NCL;++c){
    int ia = c*DD + lane, ib = ia + 64;
    float sca = sc[ia], scb = sc[ib];
    float p = fa[0]*bw[ia] + fb[0]*bw[ib];
#pragma unroll
    for (int f=1;f<8;++f)
      p += fa[f]*sw[ia*7 + f-1]*sca + fb[f]*sw[ib*7 + f-1]*scb;
#pragma unroll
    for (int o=1;o<64;o<<=1) p += __shfl_xor(p, o);
    logits[c] = p;
  }
  float mx = logits[0];
#pragma unroll
  for (int c=1;c<NCL;++c) mx = fmaxf(mx, logits[c]);
  float lse = 0.f;
#pragma unroll
  for (int c=0;c<NCL;++c) lse += __expf(logits[c]-mx);
  lse = mx + logf(lse);
  if (lane < NCL){
    float v = 0.f;
#pragma unroll
    for (int c=0;c<NCL;++c) if (lane == c) v = logits[c] - lse;
    out[g*NCL + lane] = v;
  }
}

// ---------------- host ----------------
extern "C" void kernel_launch(void* const* d_in, const int* in_sizes, int n_in,
                              void* d_out, int out_size, void* d_ws, size_t ws_size,
                              hipStream_t stream)
{
  const float* x        = (const float*)d_in[0];
  const int*   ei       = (const int*)  d_in[1];
  const int*   batch    = (const int*)  d_in[2];
  const float* base_w   = (const float*)d_in[3];
  const float* spline_w = (const float*)d_in[4];
  const float* scaler   = (const float*)d_in[5];
  const float* att_src  = (const float*)d_in[6];
  const float* att_dst  = (const float*)d_in[7];
  const float* bias     = (const float*)d_in[8];
  const float* ro_bw    = (const float*)d_in[9];
  const float* ro_sw    = (const float*)d_in[10];
  const float* ro_sc    = (const float*)d_in[11];
  float* out = (float*)d_out;

  char* p = (char*)d_ws;
  auto alloc = [&](size_t bytes)->char* {
    char* r = p;
    p += (bytes + 255) & ~(size_t)255;
    return r;
  };
  unsigned int* hpack = (unsigned int*)alloc((size_t)50048*64*4);
  float* hbuf   = (float*)alloc((size_t)NN*DD*4);
  unsigned short* wfrag = (unsigned short*)alloc((size_t)3*131072*2);
  float* asrc   = (float*)alloc((size_t)NN*4*4);
  float* adst   = (float*)alloc((size_t)NN*4*4);
  float* pooled = (float*)alloc((size_t)NGR*DD*4);
  int*   deg    = (int*)alloc((size_t)NN*4);
  int*   offs   = (int*)alloc((size_t)NN*4);
  int*   cursor = (int*)alloc((size_t)NN*4);
  int*   csr    = (int*)alloc((size_t)ETOT*4);
  unsigned* tmp = (unsigned*)alloc((size_t)ETOT*4);
  int*   bcur   = (int*)alloc((size_t)NBUK*4);
  int*   part   = (int*)alloc((size_t)256*4);

  const int nbs = (NN + 255)/256;
  hipMemsetAsync(deg, 0, (size_t)NN*sizeof(int), stream);
  hist_kernel   <<<(ETOT+255)/256, 256, 0, stream>>>(ei, deg);
  scan1_kernel  <<<nbs, 256, 0, stream>>>(deg, offs, part);
  scan2_kernel  <<<1,   256, 0, stream>>>(part, nbs);
  scan3_kernel  <<<nbs, 256, 0, stream>>>(offs, part, cursor);
  binit_kernel  <<<1,   128, 0, stream>>>(offs, bcur);
  binpass_kernel<<<256, 256, 0, stream>>>(ei, bcur, tmp);
  scatter_kernel<<<NBUK,256, 0, stream>>>(tmp, offs, cursor, csr);
  build_wfrag   <<<(3*128*1024)/256, 256, 0, stream>>>(base_w, spline_w, scaler, wfrag);

  const float* cur = x;
  for (int l=0; l<3; ++l){
    kan_gemm   <<<(NN+63)/64, 256, 0, stream>>>(cur, wfrag, att_src, att_dst,
                                                hpack, asrc, adst, l);
    attn_kernel<<<(NN+3)/4,   256, 0, stream>>>(hpack, asrc, adst, offs, deg, csr,
                                                bias, hbuf, l);
    cur = hbuf;
  }
  hipMemsetAsync(pooled, 0, (size_t)NGR*DD*sizeof(float), stream);
  pool_kernel   <<<(NN+127)/128, 128, 0, stream>>>(hbuf, batch, pooled);
  readout_kernel<<<NGR, 64, 0, stream>>>(pooled, ro_bw, ro_sw, ro_sc, out);
}